// Round 10
// baseline (1283.872 us; speedup 1.0000x reference)
//
#include <hip/hip_runtime.h>
#include <math.h>

// Problem constants: B=32, T=1024, OBS=512, H=512, DI=1024, L=2, A=16
#define MROWS 32768   // B*T
#define T_LEN 1024

typedef __attribute__((ext_vector_type(8))) short bf16x8;
typedef __attribute__((ext_vector_type(4))) float f32x4;

__device__ __forceinline__ unsigned short f2bf(float f) {
  union { float f; unsigned u; } x; x.f = f;
  unsigned r = x.u + 0x7fffu + ((x.u >> 16) & 1u);   // RNE
  return (unsigned short)(r >> 16);
}
__device__ __forceinline__ float bf2f(unsigned short u) {
  union { unsigned u; float f; } x; x.u = ((unsigned)u) << 16; return x.f;
}

__device__ __forceinline__ void gload_lds16(const void* g, void* l) {
  __builtin_amdgcn_global_load_lds(
      (const __attribute__((address_space(1))) void*)g,
      (__attribute__((address_space(3))) void*)l, 16, 0, 0);
}

// ---------------------------------------------------------------------------
// GEMM: C[M,N] = A[M,(lda)] (bf16, K cols used) * B[N,K]^T (bf16), fp32 accum.
// MODE 0: += bias[n] (f32), exact GELU, write bf16
// MODE 1: write bf16
// MODE 2: += res[m,n] (bf16, may alias outb), write bf16
// Tiles: BM=BN=128, BK=64; 4 waves; each wave 64x64 via 4x4 MFMA 16x16x32,
// two kh half-steps per K-tile. XOR-swizzled LDS (slot = chunk ^ (row&7))
// killed R5's 8.39M SQ_LDS_BANK_CONFLICT (8-way on 64B rows).
// ---------------------------------------------------------------------------
template<int MODE>
__global__ __launch_bounds__(256, 2)
void gemm_bt(const unsigned short* __restrict__ A, int lda,
             const unsigned short* __restrict__ B,
             int N, int K,
             const float* __restrict__ bias,
             const unsigned short* res,
             unsigned short* outb)
{
  __shared__ __align__(16) unsigned short sA[128 * 64];
  __shared__ __align__(16) unsigned short sB[128 * 64];
  const int tid  = threadIdx.x;
  const int wave = tid >> 6, lane = tid & 63;
  const int m0 = blockIdx.x * 128, n0 = blockIdx.y * 128;
  // staging: instr j = wave*4+i covers rows j*8..j*8+7 (8 rows x 8 chunks)
  const int srow   = lane >> 3;                   // row within 8-row group
  const int sslotb = ((lane & 7) ^ srow) * 16;    // swizzled source chunk (bytes)
  const int wm = wave & 1, wn = wave >> 1;
  const int r16 = lane & 15, q = lane >> 4;

  f32x4 acc[4][4];
#pragma unroll
  for (int i = 0; i < 4; i++)
#pragma unroll
    for (int j = 0; j < 4; j++)
#pragma unroll
      for (int e = 0; e < 4; e++) acc[i][j][e] = 0.0f;

  const char* Ab = (const char*)A;
  const char* Bb = (const char*)B;
  char* sAb = (char*)sA;
  char* sBb = (char*)sB;

  for (int kt = 0; kt < K; kt += 64) {
#pragma unroll
    for (int i = 0; i < 4; i++) {
      const int j = wave * 4 + i;
      const int row = j * 8 + srow;
      gload_lds16(Ab + ((size_t)(m0 + row) * lda + kt) * 2 + sslotb, sAb + j * 1024);
      gload_lds16(Bb + ((size_t)(n0 + row) * K   + kt) * 2 + sslotb, sBb + j * 1024);
    }
    __syncthreads();
#pragma unroll
    for (int kh = 0; kh < 2; kh++) {
      bf16x8 af[4], bfr[4];
#pragma unroll
      for (int mt = 0; mt < 4; mt++) {
        const int row = wm * 64 + mt * 16 + r16;
        af[mt] = *(const bf16x8*)(sAb + row * 128 + ((((kh << 2) | q) ^ (row & 7)) * 16));
      }
#pragma unroll
      for (int nt = 0; nt < 4; nt++) {
        const int row = wn * 64 + nt * 16 + r16;
        bfr[nt] = *(const bf16x8*)(sBb + row * 128 + ((((kh << 2) | q) ^ (row & 7)) * 16));
      }
#pragma unroll
      for (int mt = 0; mt < 4; mt++)
#pragma unroll
        for (int nt = 0; nt < 4; nt++)
          acc[mt][nt] = __builtin_amdgcn_mfma_f32_16x16x32_bf16(af[mt], bfr[nt], acc[mt][nt], 0, 0, 0);
    }
    __syncthreads();
  }

  // epilogue; C/D layout: n = lane&15, m = (lane>>4)*4 + r
#pragma unroll
  for (int mt = 0; mt < 4; mt++) {
#pragma unroll
    for (int nt = 0; nt < 4; nt++) {
#pragma unroll
      for (int r = 0; r < 4; r++) {
        const int m = m0 + wm * 64 + mt * 16 + q * 4 + r;
        const int n = n0 + wn * 64 + nt * 16 + r16;
        const size_t idx = (size_t)m * N + n;
        float v = acc[mt][nt][r];
        if (MODE == 0) {
          v += bias[n];
          v = 0.5f * v * (1.0f + erff(v * 0.70710678118654752f));
        } else if (MODE == 2) {
          v += bf2f(res[idx]);
        }
        outb[idx] = f2bf(v);
      }
    }
  }
}

// ---------------------------------------------------------------------------
// minGRU chunked parallel scan, 256-thread register-cache variant.
// History: 1024-thread blocks are HARD-capped at 64 VGPR by the allocator
// (R3/R4/R9 — launch_bounds hints ignored, every register-cache attempt
// spilled). 256-thread blocks are NOT capped (m97 GEMM: 164 VGPR). So:
// block = 256 threads = 16 chunks x 16 d-pairs, chunk length 64 ->
// pa[64]+pb[64] = 128 VGPR cache + ~30 temps ~ 160, within (256,2)'s
// 256-reg budget. Transcendentals ONCE, replay from registers, no
// extra HBM traffic (R7/R8 lesson), no spill (R9 lesson).
//   h_t = a_t*h_{t-1} + b_t;  e = exp(-gate), r = 1/(1+e): z = r,
//   a = e*r (= sigmoid(-gate), exact), b = r*g,
//   g = hid>=0 ? hid+0.5 : sigmoid(hid).
// hg: [M, 2048] bf16 (hidden | gate); h_t written over the gate slot
// (same-thread read-before-write). Block = (batch b, 32 d's); grid 32x32.
// ---------------------------------------------------------------------------
__global__ __launch_bounds__(256, 2)
void scan_kernel(unsigned short* hg) {
  __shared__ float sA[16 * 32];
  __shared__ float sH[16 * 32];
  __shared__ float sC[16 * 32];
  const int b  = blockIdx.x >> 5;      // batch
  const int dg = blockIdx.x & 31;      // 32-d group
  const int tid = threadIdx.x;
  const int c  = tid >> 4;             // chunk 0..15 (64 t each)
  const int dp = tid & 15;             // d-pair 0..15
  unsigned int* base = (unsigned int*)(hg + (size_t)b * T_LEN * 2048);
  const int du = dg * 16 + dp;         // u32 col of this thread's d-pair

  // pass 1: compute (a,b) once, cache bf16-packed in registers, summarize
  unsigned int pa[64], pb[64];
  float A0 = 1.0f, A1 = 1.0f, h0 = 0.0f, h1 = 0.0f;
#pragma unroll
  for (int tl = 0; tl < 64; ++tl) {
    const int t = c * 64 + tl;
    const unsigned hidp = base[t * 1024 + du];
    const unsigned gtp  = base[t * 1024 + 512 + du];
    const float hid0 = bf2f((unsigned short)hidp), hid1 = bf2f((unsigned short)(hidp >> 16));
    const float gt0  = bf2f((unsigned short)gtp),  gt1  = bf2f((unsigned short)(gtp >> 16));
    const float e0 = __expf(-gt0), e1 = __expf(-gt1);
    const float r0 = 1.0f / (1.0f + e0), r1 = 1.0f / (1.0f + e1);
    const float g0 = (hid0 >= 0.0f) ? (hid0 + 0.5f) : (1.0f / (1.0f + __expf(-hid0)));
    const float g1 = (hid1 >= 0.0f) ? (hid1 + 0.5f) : (1.0f / (1.0f + __expf(-hid1)));
    const unsigned short ra0 = f2bf(e0 * r0), rb0 = f2bf(r0 * g0);
    const unsigned short ra1 = f2bf(e1 * r1), rb1 = f2bf(r1 * g1);
    pa[tl] = (unsigned)ra0 | ((unsigned)ra1 << 16);
    pb[tl] = (unsigned)rb0 | ((unsigned)rb1 << 16);
    const float fa0 = bf2f(ra0), fb0 = bf2f(rb0), fa1 = bf2f(ra1), fb1 = bf2f(rb1);
    A0 *= fa0; h0 = fa0 * h0 + fb0;
    A1 *= fa1; h1 = fa1 * h1 + fb1;
  }
  sA[c * 32 + 2 * dp] = A0;  sA[c * 32 + 2 * dp + 1] = A1;
  sH[c * 32 + 2 * dp] = h0;  sH[c * 32 + 2 * dp + 1] = h1;
  __syncthreads();

  // pass 2: serial carry composition across the 16 chunks (per d)
  if (tid < 32) {
    float hin = 0.0f;
#pragma unroll
    for (int cc = 0; cc < 16; ++cc) {
      sC[cc * 32 + tid] = hin;
      hin = sH[cc * 32 + tid] + sA[cc * 32 + tid] * hin;
    }
  }
  __syncthreads();

  // pass 3: pure-FMA replay from registers; write h over the gate slot
  float hh0 = sC[c * 32 + 2 * dp];
  float hh1 = sC[c * 32 + 2 * dp + 1];
#pragma unroll
  for (int tl = 0; tl < 64; ++tl) {
    const int t = c * 64 + tl;
    const float fa0 = bf2f((unsigned short)pa[tl]), fa1 = bf2f((unsigned short)(pa[tl] >> 16));
    const float fb0 = bf2f((unsigned short)pb[tl]), fb1 = bf2f((unsigned short)(pb[tl] >> 16));
    hh0 = fa0 * hh0 + fb0;
    hh1 = fa1 * hh1 + fb1;
    base[t * 1024 + 512 + du] = (unsigned)f2bf(hh0) | ((unsigned)f2bf(hh1) << 16);
  }
}

// ---------------------------------------------------------------------------
// RMSNorm in place on bf16 h. One wave per row of 512.
// ---------------------------------------------------------------------------
__global__ __launch_bounds__(256)
void rms_kernel(unsigned short* __restrict__ hb, const float* __restrict__ w) {
  const int wid  = (blockIdx.x * blockDim.x + threadIdx.x) >> 6;
  const int lane = threadIdx.x & 63;
  unsigned short* row = hb + (size_t)wid * 512;
  float v[8];
  float ss = 0.0f;
#pragma unroll
  for (int j = 0; j < 8; j++) { v[j] = bf2f(row[lane + 64 * j]); ss += v[j] * v[j]; }
#pragma unroll
  for (int off = 32; off >= 1; off >>= 1) ss += __shfl_xor(ss, off, 64);
  const float r = rsqrtf(ss * (1.0f / 512.0f) + 1.1920929e-7f);
#pragma unroll
  for (int j = 0; j < 8; j++) {
    const int k = lane + 64 * j;
    row[k] = f2bf(v[j] * r * w[k]);
  }
}

// ---------------------------------------------------------------------------
// Decoder: logits[row,16] = h.dec_w^T + dec_b; values[row] = h.val_w + val_b.
// ---------------------------------------------------------------------------
__global__ __launch_bounds__(256)
void decoder_kernel(const unsigned short* __restrict__ hb,
                    const float* __restrict__ dec_w,
                    const float* __restrict__ dec_b,
                    const float* __restrict__ val_w,
                    const float* __restrict__ val_b,
                    float* __restrict__ out) {
  const int nw   = (gridDim.x * blockDim.x) >> 6;
  const int wid  = (blockIdx.x * blockDim.x + threadIdx.x) >> 6;
  const int lane = threadIdx.x & 63;
  float* logits = out;
  float* values = out + (size_t)MROWS * 16;
  for (int row = wid; row < MROWS; row += nw) {
    const unsigned short* hr = hb + (size_t)row * 512;
    float acc[17];
#pragma unroll
    for (int a = 0; a < 17; a++) acc[a] = 0.0f;
#pragma unroll
    for (int j = 0; j < 8; j++) {
      const int k = lane + 64 * j;
      const float hv = bf2f(hr[k]);
#pragma unroll
      for (int a = 0; a < 16; a++) acc[a] += hv * dec_w[a * 512 + k];
      acc[16] += hv * val_w[k];
    }
#pragma unroll
    for (int a = 0; a < 17; a++) {
#pragma unroll
      for (int off = 32; off >= 1; off >>= 1) acc[a] += __shfl_xor(acc[a], off, 64);
    }
    if (lane == 0) {
#pragma unroll
      for (int a = 0; a < 16; a++) logits[(size_t)row * 16 + a] = acc[a] + dec_b[a];
      values[row] = acc[16] + val_b[0];
    }
  }
}

// ---------------------------------------------------------------------------
__global__ __launch_bounds__(256)
void conv_bf16(const float* __restrict__ in, unsigned short* __restrict__ out, int n4) {
  const int i = blockIdx.x * blockDim.x + threadIdx.x;
  if (i < n4) {
    const float4 v = ((const float4*)in)[i];
    const unsigned long long pack =
        (unsigned long long)f2bf(v.x) |
        ((unsigned long long)f2bf(v.y) << 16) |
        ((unsigned long long)f2bf(v.z) << 32) |
        ((unsigned long long)f2bf(v.w) << 48);
    ((unsigned long long*)out)[i] = pack;
  }
}

// ---------------------------------------------------------------------------
// Workspace layout (bytes) — total 174,587,904 (~166.5 MiB):
//   hg   bf16 [32768,2048] @ 0          (128 MB)  [xb bf16 aliases @0 pre-encoder]
//   hb   bf16 [32768,512]  @ 134217728  (32 MB)
//   wbf  bf16 weights      @ 167772160  (~6.5 MB)
// ---------------------------------------------------------------------------
extern "C" void kernel_launch(void* const* d_in, const int* in_sizes, int n_in,
                              void* d_out, int out_size, void* d_ws, size_t ws_size,
                              hipStream_t stream) {
  const float* x     = (const float*)d_in[0];
  const float* enc_w = (const float*)d_in[1];
  const float* enc_b = (const float*)d_in[2];
  const float* w_hg  = (const float*)d_in[3];
  const float* w_out = (const float*)d_in[4];
  const float* rms_w = (const float*)d_in[5];
  const float* dec_w = (const float*)d_in[6];
  const float* dec_b = (const float*)d_in[7];
  const float* val_w = (const float*)d_in[8];
  const float* val_b = (const float*)d_in[9];
  float* out = (float*)d_out;

  if (ws_size < 174587904u) return;  // fail loudly via absmax, not via fault

  char* ws = (char*)d_ws;
  unsigned short* hg   = (unsigned short*)(ws);
  unsigned short* xb   = (unsigned short*)(ws);               // alias (encoder only)
  unsigned short* hb   = (unsigned short*)(ws + 134217728);
  unsigned short* wenc = (unsigned short*)(ws + 167772160);
  unsigned short* whg  = wenc + 262144;                       // 2 layers x 2048x512
  unsigned short* wout = whg + 2097152;                       // 2 layers x 512x1024

  // bf16 conversions (x + all matmul weights)
  conv_bf16<<<16384, 256, 0, stream>>>(x, xb, 4194304);
  conv_bf16<<<256,   256, 0, stream>>>(enc_w, wenc, 65536);
  conv_bf16<<<2048,  256, 0, stream>>>(w_hg, whg, 524288);
  conv_bf16<<<1024,  256, 0, stream>>>(w_out, wout, 262144);

  // encoder: hb = gelu(x @ enc_w^T + enc_b)
  gemm_bt<0><<<dim3(256, 4), 256, 0, stream>>>(xb, 512, wenc, 512, 512, enc_b, nullptr, hb);

  for (int l = 0; l < 2; ++l) {
    // hg = hb @ w_hg^T  [M, 2048]
    gemm_bt<1><<<dim3(256, 16), 256, 0, stream>>>(hb, 512, whg + (size_t)l * 1048576, 2048, 512,
                                                  nullptr, nullptr, hg);
    // chunked parallel scan: writes h_t over the gate half of hg
    scan_kernel<<<1024, 256, 0, stream>>>(hg);
    // hb = h(@hg+1024, lda 2048) @ w_out^T + hb  (bf16 residual, in place)
    gemm_bt<2><<<dim3(256, 4), 256, 0, stream>>>(hg + 1024, 2048, wout + (size_t)l * 524288,
                                                 512, 1024, nullptr, hb, hb);
    // RMSNorm in place
    rms_kernel<<<8192, 256, 0, stream>>>(hb, rms_w + (size_t)l * 512);
  }

  decoder_kernel<<<512, 256, 0, stream>>>(hb, dec_w, dec_b, val_w, val_b, out);
}

// Round 11
// 591.112 us; speedup vs baseline: 2.1720x; 2.1720x over previous
//
#include <hip/hip_runtime.h>
#include <math.h>

// Problem constants: B=32, T=1024, OBS=512, H=512, DI=1024, L=2, A=16
#define MROWS 32768   // B*T
#define T_LEN 1024

typedef __attribute__((ext_vector_type(8))) short bf16x8;
typedef __attribute__((ext_vector_type(4))) float f32x4;

__device__ __forceinline__ unsigned short f2bf(float f) {
  union { float f; unsigned u; } x; x.f = f;
  unsigned r = x.u + 0x7fffu + ((x.u >> 16) & 1u);   // RNE
  return (unsigned short)(r >> 16);
}
__device__ __forceinline__ float bf2f(unsigned short u) {
  union { unsigned u; float f; } x; x.u = ((unsigned)u) << 16; return x.f;
}

__device__ __forceinline__ void gload_lds16(const void* g, void* l) {
  __builtin_amdgcn_global_load_lds(
      (const __attribute__((address_space(1))) void*)g,
      (__attribute__((address_space(3))) void*)l, 16, 0, 0);
}

// ---------------------------------------------------------------------------
// GEMM: C[M,N] = A[M,(lda)] (bf16, K cols used) * B[N,K]^T (bf16), fp32 accum.
// MODE 0: += bias[n] (f32), exact GELU, write bf16
// MODE 1: write bf16
// MODE 2: += res[m,n] (bf16, may alias outb), write bf16
// Tiles: BM=BN=128, BK=64; 4 waves; each wave 64x64 via 4x4 MFMA 16x16x32,
// two kh half-steps per K-tile. XOR-swizzled LDS (slot = chunk ^ (row&7))
// killed R5's 8.39M SQ_LDS_BANK_CONFLICT (8-way on 64B rows).
// ---------------------------------------------------------------------------
template<int MODE>
__global__ __launch_bounds__(256, 2)
void gemm_bt(const unsigned short* __restrict__ A, int lda,
             const unsigned short* __restrict__ B,
             int N, int K,
             const float* __restrict__ bias,
             const unsigned short* res,
             unsigned short* outb)
{
  __shared__ __align__(16) unsigned short sA[128 * 64];
  __shared__ __align__(16) unsigned short sB[128 * 64];
  const int tid  = threadIdx.x;
  const int wave = tid >> 6, lane = tid & 63;
  const int m0 = blockIdx.x * 128, n0 = blockIdx.y * 128;
  // staging: instr j = wave*4+i covers rows j*8..j*8+7 (8 rows x 8 chunks)
  const int srow   = lane >> 3;                   // row within 8-row group
  const int sslotb = ((lane & 7) ^ srow) * 16;    // swizzled source chunk (bytes)
  const int wm = wave & 1, wn = wave >> 1;
  const int r16 = lane & 15, q = lane >> 4;

  f32x4 acc[4][4];
#pragma unroll
  for (int i = 0; i < 4; i++)
#pragma unroll
    for (int j = 0; j < 4; j++)
#pragma unroll
      for (int e = 0; e < 4; e++) acc[i][j][e] = 0.0f;

  const char* Ab = (const char*)A;
  const char* Bb = (const char*)B;
  char* sAb = (char*)sA;
  char* sBb = (char*)sB;

  for (int kt = 0; kt < K; kt += 64) {
#pragma unroll
    for (int i = 0; i < 4; i++) {
      const int j = wave * 4 + i;
      const int row = j * 8 + srow;
      gload_lds16(Ab + ((size_t)(m0 + row) * lda + kt) * 2 + sslotb, sAb + j * 1024);
      gload_lds16(Bb + ((size_t)(n0 + row) * K   + kt) * 2 + sslotb, sBb + j * 1024);
    }
    __syncthreads();
#pragma unroll
    for (int kh = 0; kh < 2; kh++) {
      bf16x8 af[4], bfr[4];
#pragma unroll
      for (int mt = 0; mt < 4; mt++) {
        const int row = wm * 64 + mt * 16 + r16;
        af[mt] = *(const bf16x8*)(sAb + row * 128 + ((((kh << 2) | q) ^ (row & 7)) * 16));
      }
#pragma unroll
      for (int nt = 0; nt < 4; nt++) {
        const int row = wn * 64 + nt * 16 + r16;
        bfr[nt] = *(const bf16x8*)(sBb + row * 128 + ((((kh << 2) | q) ^ (row & 7)) * 16));
      }
#pragma unroll
      for (int mt = 0; mt < 4; mt++)
#pragma unroll
        for (int nt = 0; nt < 4; nt++)
          acc[mt][nt] = __builtin_amdgcn_mfma_f32_16x16x32_bf16(af[mt], bfr[nt], acc[mt][nt], 0, 0, 0);
    }
    __syncthreads();
  }

  // epilogue; C/D layout: n = lane&15, m = (lane>>4)*4 + r
#pragma unroll
  for (int mt = 0; mt < 4; mt++) {
#pragma unroll
    for (int nt = 0; nt < 4; nt++) {
#pragma unroll
      for (int r = 0; r < 4; r++) {
        const int m = m0 + wm * 64 + mt * 16 + q * 4 + r;
        const int n = n0 + wn * 64 + nt * 16 + r16;
        const size_t idx = (size_t)m * N + n;
        float v = acc[mt][nt][r];
        if (MODE == 0) {
          v += bias[n];
          v = 0.5f * v * (1.0f + erff(v * 0.70710678118654752f));
        } else if (MODE == 2) {
          v += bf2f(res[idx]);
        }
        outb[idx] = f2bf(v);
      }
    }
  }
}

// ---------------------------------------------------------------------------
// minGRU chunked parallel scan, LDS-cache variant.
// History: register caches always spill — allocator grants 64 VGPR @1024thr
// (R3/R4/R9) and 128 @256thr (R10), both one notch under the cache's need.
// Recompute (R6, 86.6us) doubles transcendentals (VALUBusy 77%); global
// (a,b) stores (R7/R8) trade the VALU back as HBM bytes. LDS is the tier
// that works: pass 1 computes (a,b) ONCE, caches them bf16-packed in LDS;
// pass 3 replays pure-FMA from LDS. T processed in 4 segments of 256 so the
// cache is 256 x 16dp x 8B = 32KB (+4KB summaries = 36KB -> 4 blocks/CU);
// inter-segment carry lives in registers of lanes tid<32.
//   h_t = a_t*h_{t-1} + b_t;  e = exp(-gate), r = 1/(1+e): z = r,
//   a = e*r (= sigmoid(-gate)), b = r*g, g = hid>=0 ? hid+0.5 : sigmoid(hid).
// hg: [M, 2048] bf16 (hidden | gate); h_t written over the gate slot
// (same-thread read-before-write). Block = (batch b, 32 d's) = 256 threads
// = 16 chunks x 16 d-pairs, 16 t-steps per chunk per segment. Grid 32x32.
// ---------------------------------------------------------------------------
__global__ __launch_bounds__(256)
void scan_kernel(unsigned short* hg) {
  __shared__ unsigned long long sAB[256 * 16];   // [t_local][dp]: lo=a-pair, hi=b-pair
  __shared__ float sA[16 * 32];                  // [chunk][d]: A-prod, then carry
  __shared__ float sH[16 * 32];                  // [chunk][d]: local scan sum
  const int b  = blockIdx.x >> 5;      // batch
  const int dg = blockIdx.x & 31;      // 32-d group
  const int tid = threadIdx.x;
  const int c  = tid >> 4;             // chunk 0..15
  const int dp = tid & 15;             // d-pair 0..15
  unsigned int* base = (unsigned int*)(hg + (size_t)b * T_LEN * 2048);
  const int du = dg * 16 + dp;         // u32 col of this thread's d-pair

  float carry = 0.0f;                  // per-d carry, lanes tid<32 only

  for (int seg = 0; seg < 4; ++seg) {
    const int t0 = seg * 256 + c * 16;

    // pass 1: compute (a,b) once, cache in LDS, accumulate chunk summary
    float A0 = 1.0f, A1 = 1.0f, h0 = 0.0f, h1 = 0.0f;
#pragma unroll
    for (int tl = 0; tl < 16; ++tl) {
      const int t = t0 + tl;
      const unsigned hidp = base[t * 1024 + du];
      const unsigned gtp  = base[t * 1024 + 512 + du];
      const float hid0 = bf2f((unsigned short)hidp), hid1 = bf2f((unsigned short)(hidp >> 16));
      const float gt0  = bf2f((unsigned short)gtp),  gt1  = bf2f((unsigned short)(gtp >> 16));
      const float e0 = __expf(-gt0), e1 = __expf(-gt1);
      const float r0 = 1.0f / (1.0f + e0), r1 = 1.0f / (1.0f + e1);
      const float g0 = (hid0 >= 0.0f) ? (hid0 + 0.5f) : (1.0f / (1.0f + __expf(-hid0)));
      const float g1 = (hid1 >= 0.0f) ? (hid1 + 0.5f) : (1.0f / (1.0f + __expf(-hid1)));
      const unsigned short ra0 = f2bf(e0 * r0), rb0 = f2bf(r0 * g0);
      const unsigned short ra1 = f2bf(e1 * r1), rb1 = f2bf(r1 * g1);
      sAB[(c * 16 + tl) * 16 + dp] =
          (unsigned long long)((unsigned)ra0 | ((unsigned)ra1 << 16)) |
          ((unsigned long long)((unsigned)rb0 | ((unsigned)rb1 << 16)) << 32);
      const float fa0 = bf2f(ra0), fb0 = bf2f(rb0), fa1 = bf2f(ra1), fb1 = bf2f(rb1);
      A0 *= fa0; h0 = fa0 * h0 + fb0;
      A1 *= fa1; h1 = fa1 * h1 + fb1;
    }
    sA[c * 32 + 2 * dp] = A0;  sA[c * 32 + 2 * dp + 1] = A1;
    sH[c * 32 + 2 * dp] = h0;  sH[c * 32 + 2 * dp + 1] = h1;
    __syncthreads();

    // pass 2: serial carry composition (one lane per d); overwrite sA w/ carry
    if (tid < 32) {
      float hin = carry;
#pragma unroll
      for (int cc = 0; cc < 16; ++cc) {
        const float a  = sA[cc * 32 + tid];
        const float hs = sH[cc * 32 + tid];
        sA[cc * 32 + tid] = hin;
        hin = hs + a * hin;
      }
      carry = hin;
    }
    __syncthreads();

    // pass 3: pure-FMA replay from LDS; write h over the gate slot
    float hh0 = sA[c * 32 + 2 * dp];
    float hh1 = sA[c * 32 + 2 * dp + 1];
#pragma unroll
    for (int tl = 0; tl < 16; ++tl) {
      const int t = t0 + tl;
      const unsigned long long ab = sAB[(c * 16 + tl) * 16 + dp];
      const float fa0 = bf2f((unsigned short)ab);
      const float fa1 = bf2f((unsigned short)(ab >> 16));
      const float fb0 = bf2f((unsigned short)(ab >> 32));
      const float fb1 = bf2f((unsigned short)(ab >> 48));
      hh0 = fa0 * hh0 + fb0;
      hh1 = fa1 * hh1 + fb1;
      base[t * 1024 + 512 + du] = (unsigned)f2bf(hh0) | ((unsigned)f2bf(hh1) << 16);
    }
    __syncthreads();   // sAB/sA/sH reused next segment
  }
}

// ---------------------------------------------------------------------------
// RMSNorm in place on bf16 h. One wave per row of 512.
// ---------------------------------------------------------------------------
__global__ __launch_bounds__(256)
void rms_kernel(unsigned short* __restrict__ hb, const float* __restrict__ w) {
  const int wid  = (blockIdx.x * blockDim.x + threadIdx.x) >> 6;
  const int lane = threadIdx.x & 63;
  unsigned short* row = hb + (size_t)wid * 512;
  float v[8];
  float ss = 0.0f;
#pragma unroll
  for (int j = 0; j < 8; j++) { v[j] = bf2f(row[lane + 64 * j]); ss += v[j] * v[j]; }
#pragma unroll
  for (int off = 32; off >= 1; off >>= 1) ss += __shfl_xor(ss, off, 64);
  const float r = rsqrtf(ss * (1.0f / 512.0f) + 1.1920929e-7f);
#pragma unroll
  for (int j = 0; j < 8; j++) {
    const int k = lane + 64 * j;
    row[k] = f2bf(v[j] * r * w[k]);
  }
}

// ---------------------------------------------------------------------------
// Decoder: logits[row,16] = h.dec_w^T + dec_b; values[row] = h.val_w + val_b.
// ---------------------------------------------------------------------------
__global__ __launch_bounds__(256)
void decoder_kernel(const unsigned short* __restrict__ hb,
                    const float* __restrict__ dec_w,
                    const float* __restrict__ dec_b,
                    const float* __restrict__ val_w,
                    const float* __restrict__ val_b,
                    float* __restrict__ out) {
  const int nw   = (gridDim.x * blockDim.x) >> 6;
  const int wid  = (blockIdx.x * blockDim.x + threadIdx.x) >> 6;
  const int lane = threadIdx.x & 63;
  float* logits = out;
  float* values = out + (size_t)MROWS * 16;
  for (int row = wid; row < MROWS; row += nw) {
    const unsigned short* hr = hb + (size_t)row * 512;
    float acc[17];
#pragma unroll
    for (int a = 0; a < 17; a++) acc[a] = 0.0f;
#pragma unroll
    for (int j = 0; j < 8; j++) {
      const int k = lane + 64 * j;
      const float hv = bf2f(hr[k]);
#pragma unroll
      for (int a = 0; a < 16; a++) acc[a] += hv * dec_w[a * 512 + k];
      acc[16] += hv * val_w[k];
    }
#pragma unroll
    for (int a = 0; a < 17; a++) {
#pragma unroll
      for (int off = 32; off >= 1; off >>= 1) acc[a] += __shfl_xor(acc[a], off, 64);
    }
    if (lane == 0) {
#pragma unroll
      for (int a = 0; a < 16; a++) logits[(size_t)row * 16 + a] = acc[a] + dec_b[a];
      values[row] = acc[16] + val_b[0];
    }
  }
}

// ---------------------------------------------------------------------------
__global__ __launch_bounds__(256)
void conv_bf16(const float* __restrict__ in, unsigned short* __restrict__ out, int n4) {
  const int i = blockIdx.x * blockDim.x + threadIdx.x;
  if (i < n4) {
    const float4 v = ((const float4*)in)[i];
    const unsigned long long pack =
        (unsigned long long)f2bf(v.x) |
        ((unsigned long long)f2bf(v.y) << 16) |
        ((unsigned long long)f2bf(v.z) << 32) |
        ((unsigned long long)f2bf(v.w) << 48);
    ((unsigned long long*)out)[i] = pack;
  }
}

// ---------------------------------------------------------------------------
// Workspace layout (bytes) — total 174,587,904 (~166.5 MiB):
//   hg   bf16 [32768,2048] @ 0          (128 MB)  [xb bf16 aliases @0 pre-encoder]
//   hb   bf16 [32768,512]  @ 134217728  (32 MB)
//   wbf  bf16 weights      @ 167772160  (~6.5 MB)
// ---------------------------------------------------------------------------
extern "C" void kernel_launch(void* const* d_in, const int* in_sizes, int n_in,
                              void* d_out, int out_size, void* d_ws, size_t ws_size,
                              hipStream_t stream) {
  const float* x     = (const float*)d_in[0];
  const float* enc_w = (const float*)d_in[1];
  const float* enc_b = (const float*)d_in[2];
  const float* w_hg  = (const float*)d_in[3];
  const float* w_out = (const float*)d_in[4];
  const float* rms_w = (const float*)d_in[5];
  const float* dec_w = (const float*)d_in[6];
  const float* dec_b = (const float*)d_in[7];
  const float* val_w = (const float*)d_in[8];
  const float* val_b = (const float*)d_in[9];
  float* out = (float*)d_out;

  if (ws_size < 174587904u) return;  // fail loudly via absmax, not via fault

  char* ws = (char*)d_ws;
  unsigned short* hg   = (unsigned short*)(ws);
  unsigned short* xb   = (unsigned short*)(ws);               // alias (encoder only)
  unsigned short* hb   = (unsigned short*)(ws + 134217728);
  unsigned short* wenc = (unsigned short*)(ws + 167772160);
  unsigned short* whg  = wenc + 262144;                       // 2 layers x 2048x512
  unsigned short* wout = whg + 2097152;                       // 2 layers x 512x1024

  // bf16 conversions (x + all matmul weights)
  conv_bf16<<<16384, 256, 0, stream>>>(x, xb, 4194304);
  conv_bf16<<<256,   256, 0, stream>>>(enc_w, wenc, 65536);
  conv_bf16<<<2048,  256, 0, stream>>>(w_hg, whg, 524288);
  conv_bf16<<<1024,  256, 0, stream>>>(w_out, wout, 262144);

  // encoder: hb = gelu(x @ enc_w^T + enc_b)
  gemm_bt<0><<<dim3(256, 4), 256, 0, stream>>>(xb, 512, wenc, 512, 512, enc_b, nullptr, hb);

  for (int l = 0; l < 2; ++l) {
    // hg = hb @ w_hg^T  [M, 2048]
    gemm_bt<1><<<dim3(256, 16), 256, 0, stream>>>(hb, 512, whg + (size_t)l * 1048576, 2048, 512,
                                                  nullptr, nullptr, hg);
    // LDS-cached chunked parallel scan: writes h_t over the gate half of hg
    scan_kernel<<<1024, 256, 0, stream>>>(hg);
    // hb = h(@hg+1024, lda 2048) @ w_out^T + hb  (bf16 residual, in place)
    gemm_bt<2><<<dim3(256, 4), 256, 0, stream>>>(hg + 1024, 2048, wout + (size_t)l * 524288,
                                                 512, 1024, nullptr, hb, hb);
    // RMSNorm in place
    rms_kernel<<<8192, 256, 0, stream>>>(hb, rms_w + (size_t)l * 512);
  }

  decoder_kernel<<<512, 256, 0, stream>>>(hb, dec_w, dec_b, val_w, val_b, out);
}